// Round 13
// baseline (50.169 us; speedup 1.0000x reference)
//
#include <hip/hip_runtime.h>
#include <math.h>

#define HH 256
#define WW 256
#define BB 32
#define NW 8  // 256 rows = 8 x u32 words per column bitmask

// MEASUREMENT ROUND: stripe_kernel body repeated x4 (idempotent; ticket fires
// exactly once; LDS WAR barrier per rep) so it clears the ~40us harness fills
// and appears in rocprof top-5 with counters.  t_stripe = dur/4.
#define REP_ST 4

// ---------------------------------------------------------------------------
// Kernel A: build column bitmasks.  P bit = (pred > 0.5), T bit = (target==1).
// Also zeroes the ticket counter for kernel B (stream-ordered before it).
// ---------------------------------------------------------------------------
__global__ __launch_bounds__(256) void bitmask_kernel(
    const float* __restrict__ pred, const float* __restrict__ tgt,
    unsigned int* __restrict__ P, unsigned int* __restrict__ T,
    unsigned int* __restrict__ cnt) {
  if (blockIdx.x == 0 && threadIdx.x == 0)
    __hip_atomic_store(cnt, 0u, __ATOMIC_RELAXED, __HIP_MEMORY_SCOPE_AGENT);

  const int b  = blockIdx.x >> 5;
  const int j  = (blockIdx.x >> 2) & 7;
  const int wq = blockIdx.x & 3;
  const int r    = threadIdx.x >> 6;
  const int lane = threadIdx.x & 63;
  const int col  = wq * 64 + lane;
  const int row0 = j * 32 + r * 8;

  const float* pin = pred + (size_t)b * (HH * WW) + row0 * WW + col;
  const float* tin = tgt  + (size_t)b * (HH * WW) + row0 * WW + col;
  unsigned int pb = 0, tb = 0;
#pragma unroll
  for (int i = 0; i < 8; ++i) {
    pb |= (pin[i * WW] > 0.5f ? 1u : 0u) << i;
    tb |= (tin[i * WW] == 1.0f ? 1u : 0u) << i;
  }

  __shared__ unsigned int sP[4][64], sT[4][64];
  sP[r][lane] = pb << (r * 8);
  sT[r][lane] = tb << (r * 8);
  __syncthreads();
  if (r == 0) {
    P[((size_t)b * NW + j) * WW + col] =
        sP[0][lane] | sP[1][lane] | sP[2][lane] | sP[3][lane];
    T[((size_t)b * NW + j) * WW + col] =
        sT[0][lane] | sT[1][lane] | sT[2][lane] | sT[3][lane];
  }
}

// ---------------------------------------------------------------------------
// Kernel B (R12 structure, rep x4): 256 blocks x 512 thr, 32-row stripe.
// ---------------------------------------------------------------------------
__global__ __launch_bounds__(512) void stripe_kernel(
    const unsigned int* __restrict__ P, const unsigned int* __restrict__ T,
    float* __restrict__ partial, unsigned int* __restrict__ cnt,
    float* __restrict__ out) {
  const int blk = blockIdx.x;          // b*8 + j
  const int b = blk >> 3;
  const int j = blk & 7;
  const int tid = threadIdx.x;

  __shared__ float2 sv[32][WW];        // 64 KB: {pred, target} signed g^2
  __shared__ double sd[512];
  __shared__ unsigned int isLast;

  for (int rep = 0; rep < REP_ST; ++rep) {
    // ---- phase 1: column chains (one map per thread-half) ----
    {
      const int mp = tid >> 8;         // 0: pred, 1: target
      const int w  = tid & 255;
      const unsigned int* M = mp ? T : P;

      unsigned int Wd[NW];
#pragma unroll
      for (int jj = 0; jj < NW; ++jj)
        Wd[jj] = M[((size_t)b * NW + jj) * WW + w];

      unsigned int E[NW];
#pragma unroll
      for (int jj = 0; jj < NW - 1; ++jj)
        E[jj] = Wd[jj] ^ ((Wd[jj] >> 1) | (Wd[jj + 1] << 31));
      E[NW - 1] = (Wd[NW - 1] ^ (Wd[NW - 1] >> 1)) & 0x7FFFFFFFu;

      unsigned int EJ = 0, EJm1 = 0, WJ = 0;
#pragma unroll
      for (int jj = 0; jj < NW; ++jj) {
        if (j == jj) { EJ = E[jj]; WJ = Wd[jj]; }
        if (j - 1 == jj) EJm1 = E[jj];
      }

      int emax = -100000;
#pragma unroll
      for (int jj = 0; jj < NW - 1; ++jj)
        if (jj < j && E[jj]) emax = 32 * jj + 31 - __builtin_clz(E[jj]);
      int D = (j * 32 - 1) - emax;
      if (D > 513) D = 513;

      int emin = 100000;
#pragma unroll
      for (int jj = NW - 1; jj >= 1; --jj)
        if (jj > j && E[jj]) emin = 32 * jj + __builtin_ctz(E[jj]);
      int U = (emin + 1) - (j * 32 + 32);
      if (U > 513) U = 513;

      const unsigned int EQ = (EJ << 1) | (j ? (EJm1 >> 31) : 0u);

      unsigned int dn[16];
#pragma unroll
      for (int i = 0; i < 32; ++i) {
        D = ((EQ >> i) & 1u) ? 1 : (D + 1);
        if (i & 1) dn[i >> 1] |= (unsigned int)D << 16;
        else       dn[i >> 1] = (unsigned int)D;
      }

#pragma unroll
      for (int i = 31; i >= 0; --i) {
        U = ((EJ >> i) & 1u) ? 1 : (U + 1);
        int dnv = (int)((dn[i >> 1] >> ((i & 1) * 16)) & 0xFFFFu);
        int g = min(min(dnv, U), 512);
        float g2 = (float)(g * g);
        float v = ((WJ >> i) & 1u) ? -g2 : g2;
        *(((float*)&sv[i][w]) + mp) = v;
      }
    }
    __syncthreads();

    // ---- phase 2: 4 rows per wave, XOR-fold min-plus ----
    const int wv = tid >> 6;
    const int lane = tid & 63;
    float acc = 0.f;

    for (int rr = 0; rr < 4; ++rr) {
      const int r = wv * 4 + rr;

      float m1[4], m2[4];
      unsigned int sg1[4], sg2[4];
#pragma unroll
      for (int c = 0; c < 4; ++c) {
        float2 v = sv[r][lane + 64 * c];
        sg1[c] = __float_as_uint(v.x) & 0x80000000u;
        sg2[c] = __float_as_uint(v.y) & 0x80000000u;
        m1[c] = fabsf(v.x);
        m2[c] = fabsf(v.y);
      }

      for (int k = 1; k < WW; ++k) {
        const float c2 = (float)(k * k);
        // max3-friendly nesting: 8-value tree in ~4 instrs
        float t1 = fmaxf(fmaxf(m1[0], m1[1]), m1[2]);
        float t2 = fmaxf(fmaxf(m1[3], m2[0]), m2[1]);
        float mx = fmaxf(fmaxf(fmaxf(t1, t2), m2[2]), m2[3]);
        if (c2 >= mx) break;           // exact: remaining candidates >= k^2
#pragma unroll
        for (int c = 0; c < 4; ++c) {
          const int y = lane + 64 * c;
          const int lo = y - k;
          if (lo >= 0) {
            float2 v = sv[r][lo];
            m1[c] = fminf(m1[c],
                fmaxf(__uint_as_float(__float_as_uint(v.x) ^ sg1[c]), 0.f) + c2);
            m2[c] = fminf(m2[c],
                fmaxf(__uint_as_float(__float_as_uint(v.y) ^ sg2[c]), 0.f) + c2);
          }
          const int hi = y + k;
          if (hi < WW) {
            float2 v = sv[r][hi];
            m1[c] = fminf(m1[c],
                fmaxf(__uint_as_float(__float_as_uint(v.x) ^ sg1[c]), 0.f) + c2);
            m2[c] = fminf(m2[c],
                fmaxf(__uint_as_float(__float_as_uint(v.y) ^ sg2[c]), 0.f) + c2);
          }
        }
      }

#pragma unroll
      for (int c = 0; c < 4; ++c) {
        float pd = sqrtf(m1[c]);
        float td = sqrtf(m2[c]);
        float diff = pd - td;
        acc += diff * diff * (td * td);
      }
    }

    for (int off = 32; off > 0; off >>= 1) acc += __shfl_down(acc, off);
    if (lane == 0)
      __hip_atomic_store(&partial[blk * 8 + wv], acc, __ATOMIC_RELAXED,
                         __HIP_MEMORY_SCOPE_AGENT);

    // ---- ticket: fires exactly once across all reps ----
    __syncthreads();
    if (tid == 0) {
      unsigned int old = __hip_atomic_fetch_add(cnt, 1u, __ATOMIC_ACQ_REL,
                                                __HIP_MEMORY_SCOPE_AGENT);
      isLast = (old == (unsigned int)(BB * NW - 1)) ? 1u : 0u;
    }
    __syncthreads();
    if (isLast) {
      double s = 0.0;
      for (int i = tid; i < BB * NW * 8; i += 512)
        s += (double)__hip_atomic_load(&partial[i], __ATOMIC_RELAXED,
                                       __HIP_MEMORY_SCOPE_AGENT);
      sd[tid] = s;
      __syncthreads();
      for (int st = 256; st > 0; st >>= 1) {
        if (tid < st) sd[tid] += sd[tid + st];
        __syncthreads();
      }
      if (tid == 0)
        out[0] = (float)(sd[0] / (double)((size_t)BB * HH * WW));
      __syncthreads();
    }
    __syncthreads();                    // LDS WAR safety for next rep
    asm volatile("" ::: "memory");      // keep reps live
  }
}

extern "C" void kernel_launch(void* const* d_in, const int* in_sizes, int n_in,
                              void* d_out, int out_size, void* d_ws, size_t ws_size,
                              hipStream_t stream) {
  const float* pred = (const float*)d_in[0];
  const float* tgt  = (const float*)d_in[1];
  float* out = (float*)d_out;

  // ws: P (256 KB), T (256 KB), partial (8 KB), cnt (4 B)
  unsigned int* P = (unsigned int*)d_ws;
  unsigned int* T = P + (size_t)BB * NW * WW;
  float* partial = (float*)(T + (size_t)BB * NW * WW);
  unsigned int* cnt = (unsigned int*)(partial + BB * NW * 8);

  hipLaunchKernelGGL(bitmask_kernel, dim3(BB * NW * 4), dim3(256), 0, stream,
                     pred, tgt, P, T, cnt);
  hipLaunchKernelGGL(stripe_kernel, dim3(BB * NW), dim3(512), 0, stream,
                     P, T, partial, cnt, out);
}

// Round 14
// 24.333 us; speedup vs baseline: 2.0618x; 2.0618x over previous
//
#include <hip/hip_runtime.h>
#include <math.h>

#define HH 256
#define WW 256
#define BB 32
#define NW 8  // 256 rows = 8 x u32 words per column bitmask

// ---------------------------------------------------------------------------
// Kernel A: build column bitmasks.  P bit = (pred > 0.5), T bit = (target==1).
// Also zeroes the ticket counter for kernel B (stream-ordered before it).
// Measured ~0.3us.
// ---------------------------------------------------------------------------
__global__ __launch_bounds__(256) void bitmask_kernel(
    const float* __restrict__ pred, const float* __restrict__ tgt,
    unsigned int* __restrict__ P, unsigned int* __restrict__ T,
    unsigned int* __restrict__ cnt) {
  if (blockIdx.x == 0 && threadIdx.x == 0)
    __hip_atomic_store(cnt, 0u, __ATOMIC_RELAXED, __HIP_MEMORY_SCOPE_AGENT);

  const int b  = blockIdx.x >> 5;
  const int j  = (blockIdx.x >> 2) & 7;
  const int wq = blockIdx.x & 3;
  const int r    = threadIdx.x >> 6;
  const int lane = threadIdx.x & 63;
  const int col  = wq * 64 + lane;
  const int row0 = j * 32 + r * 8;

  const float* pin = pred + (size_t)b * (HH * WW) + row0 * WW + col;
  const float* tin = tgt  + (size_t)b * (HH * WW) + row0 * WW + col;
  unsigned int pb = 0, tb = 0;
#pragma unroll
  for (int i = 0; i < 8; ++i) {
    pb |= (pin[i * WW] > 0.5f ? 1u : 0u) << i;
    tb |= (tin[i * WW] == 1.0f ? 1u : 0u) << i;
  }

  __shared__ unsigned int sP[4][64], sT[4][64];
  sP[r][lane] = pb << (r * 8);
  sT[r][lane] = tb << (r * 8);
  __syncthreads();
  if (r == 0) {
    P[((size_t)b * NW + j) * WW + col] =
        sP[0][lane] | sP[1][lane] | sP[2][lane] | sP[3][lane];
    T[((size_t)b * NW + j) * WW + col] =
        sT[0][lane] | sT[1][lane] | sT[2][lane] | sT[3][lane];
  }
}

// ---------------------------------------------------------------------------
// Kernel B (R12 structure, 1024-THREAD BLOCKS = 16 waves/CU, 2x occupancy):
// 256 blocks, 32-row stripe.  Phase 1 identical to R12 (threads 0-511 only;
// waves 8-15 wait at the barrier — phase 1 is ~10% of block work).  Phase 2:
// 16 waves x 2 rows each (was 8 x 4) — same total work, double latency
// hiding for the stall-bound (VALUBusy 44%) XOR-fold min-plus.
// ---------------------------------------------------------------------------
__global__ __launch_bounds__(1024) void stripe_kernel(
    const unsigned int* __restrict__ P, const unsigned int* __restrict__ T,
    float* __restrict__ partial, unsigned int* __restrict__ cnt,
    float* __restrict__ out) {
  const int blk = blockIdx.x;          // b*8 + j
  const int b = blk >> 3;
  const int j = blk & 7;
  const int tid = threadIdx.x;

  __shared__ float2 sv[32][WW];        // 64 KB: {pred, target} signed g^2
  __shared__ double sd[1024];
  __shared__ unsigned int isLast;

  // ---- phase 1: column chains (threads 0-511; one map per thread-half) ----
  if (tid < 512) {
    const int mp = tid >> 8;           // 0: pred, 1: target
    const int w  = tid & 255;
    const unsigned int* M = mp ? T : P;

    unsigned int Wd[NW];
#pragma unroll
    for (int jj = 0; jj < NW; ++jj)
      Wd[jj] = M[((size_t)b * NW + jj) * WW + w];

    unsigned int E[NW];
#pragma unroll
    for (int jj = 0; jj < NW - 1; ++jj)
      E[jj] = Wd[jj] ^ ((Wd[jj] >> 1) | (Wd[jj + 1] << 31));
    E[NW - 1] = (Wd[NW - 1] ^ (Wd[NW - 1] >> 1)) & 0x7FFFFFFFu;

    unsigned int EJ = 0, EJm1 = 0, WJ = 0;
#pragma unroll
    for (int jj = 0; jj < NW; ++jj) {
      if (j == jj) { EJ = E[jj]; WJ = Wd[jj]; }
      if (j - 1 == jj) EJm1 = E[jj];
    }

    int emax = -100000;
#pragma unroll
    for (int jj = 0; jj < NW - 1; ++jj)
      if (jj < j && E[jj]) emax = 32 * jj + 31 - __builtin_clz(E[jj]);
    int D = (j * 32 - 1) - emax;
    if (D > 513) D = 513;

    int emin = 100000;
#pragma unroll
    for (int jj = NW - 1; jj >= 1; --jj)
      if (jj > j && E[jj]) emin = 32 * jj + __builtin_ctz(E[jj]);
    int U = (emin + 1) - (j * 32 + 32);
    if (U > 513) U = 513;

    const unsigned int EQ = (EJ << 1) | (j ? (EJm1 >> 31) : 0u);

    unsigned int dn[16];
#pragma unroll
    for (int i = 0; i < 32; ++i) {
      D = ((EQ >> i) & 1u) ? 1 : (D + 1);
      if (i & 1) dn[i >> 1] |= (unsigned int)D << 16;
      else       dn[i >> 1] = (unsigned int)D;
    }

#pragma unroll
    for (int i = 31; i >= 0; --i) {
      U = ((EJ >> i) & 1u) ? 1 : (U + 1);
      int dnv = (int)((dn[i >> 1] >> ((i & 1) * 16)) & 0xFFFFu);
      int g = min(min(dnv, U), 512);   // cap = H+W (exact, incl. empty cols)
      float g2 = (float)(g * g);
      float v = ((WJ >> i) & 1u) ? -g2 : g2;
      *(((float*)&sv[i][w]) + mp) = v; // mp=0 -> .x, mp=1 -> .y
    }
  }
  __syncthreads();

  // ---- phase 2: 2 rows per wave (16 waves), XOR-fold min-plus ----
  const int wv = tid >> 6;             // 0..15
  const int lane = tid & 63;
  float acc = 0.f;

  for (int rr = 0; rr < 2; ++rr) {
    const int r = wv * 2 + rr;

    float m1[4], m2[4];                // tracked (differing-class) mins
    unsigned int sg1[4], sg2[4];       // own-sign masks (0 or 0x80000000)
#pragma unroll
    for (int c = 0; c < 4; ++c) {
      float2 v = sv[r][lane + 64 * c];
      sg1[c] = __float_as_uint(v.x) & 0x80000000u;
      sg2[c] = __float_as_uint(v.y) & 0x80000000u;
      m1[c] = fabsf(v.x);              // self candidate (offset 0)
      m2[c] = fabsf(v.y);
    }

    for (int k = 1; k < WW; ++k) {
      const float c2 = (float)(k * k);
      float t1 = fmaxf(fmaxf(m1[0], m1[1]), m1[2]);
      float t2 = fmaxf(fmaxf(m1[3], m2[0]), m2[1]);
      float mx = fmaxf(fmaxf(fmaxf(t1, t2), m2[2]), m2[3]);
      if (c2 >= mx) break;             // exact: remaining candidates >= k^2
#pragma unroll
      for (int c = 0; c < 4; ++c) {
        const int y = lane + 64 * c;
        const int lo = y - k;
        if (lo >= 0) {
          float2 v = sv[r][lo];
          m1[c] = fminf(m1[c],
              fmaxf(__uint_as_float(__float_as_uint(v.x) ^ sg1[c]), 0.f) + c2);
          m2[c] = fminf(m2[c],
              fmaxf(__uint_as_float(__float_as_uint(v.y) ^ sg2[c]), 0.f) + c2);
        }
        const int hi = y + k;
        if (hi < WW) {
          float2 v = sv[r][hi];
          m1[c] = fminf(m1[c],
              fmaxf(__uint_as_float(__float_as_uint(v.x) ^ sg1[c]), 0.f) + c2);
          m2[c] = fminf(m2[c],
              fmaxf(__uint_as_float(__float_as_uint(v.y) ^ sg2[c]), 0.f) + c2);
        }
      }
    }

#pragma unroll
    for (int c = 0; c < 4; ++c) {
      float pd = sqrtf(m1[c]);         // pred_dist (own-class term is 0)
      float td = sqrtf(m2[c]);         // target_dist
      float diff = pd - td;
      acc += diff * diff * (td * td);  // matches reference rounding
    }
  }

  for (int off = 32; off > 0; off >>= 1) acc += __shfl_down(acc, off);
  if (lane == 0)
    __hip_atomic_store(&partial[blk * 16 + wv], acc, __ATOMIC_RELAXED,
                       __HIP_MEMORY_SCOPE_AGENT);

  // ---- ticket: last block reduces all 4096 partials, writes mean ----
  __syncthreads();
  if (tid == 0) {
    unsigned int old = __hip_atomic_fetch_add(cnt, 1u, __ATOMIC_ACQ_REL,
                                              __HIP_MEMORY_SCOPE_AGENT);
    isLast = (old == (unsigned int)(BB * NW - 1)) ? 1u : 0u;
  }
  __syncthreads();
  if (isLast) {
    double s = 0.0;
    for (int i = tid; i < BB * NW * 16; i += 1024)
      s += (double)__hip_atomic_load(&partial[i], __ATOMIC_RELAXED,
                                     __HIP_MEMORY_SCOPE_AGENT);
    sd[tid] = s;
    __syncthreads();
    for (int st = 512; st > 0; st >>= 1) {
      if (tid < st) sd[tid] += sd[tid + st];
      __syncthreads();
    }
    if (tid == 0)
      out[0] = (float)(sd[0] / (double)((size_t)BB * HH * WW));
  }
}

extern "C" void kernel_launch(void* const* d_in, const int* in_sizes, int n_in,
                              void* d_out, int out_size, void* d_ws, size_t ws_size,
                              hipStream_t stream) {
  const float* pred = (const float*)d_in[0];
  const float* tgt  = (const float*)d_in[1];
  float* out = (float*)d_out;

  // ws: P (256 KB), T (256 KB), partial (16 KB), cnt (4 B)
  unsigned int* P = (unsigned int*)d_ws;
  unsigned int* T = P + (size_t)BB * NW * WW;
  float* partial = (float*)(T + (size_t)BB * NW * WW);
  unsigned int* cnt = (unsigned int*)(partial + BB * NW * 16);

  hipLaunchKernelGGL(bitmask_kernel, dim3(BB * NW * 4), dim3(256), 0, stream,
                     pred, tgt, P, T, cnt);
  hipLaunchKernelGGL(stripe_kernel, dim3(BB * NW), dim3(1024), 0, stream,
                     P, T, partial, cnt, out);
}